// Round 1
// 139.756 us; speedup vs baseline: 1.0675x; 1.0675x over previous
//
#include <hip/hip_runtime.h>

typedef __attribute__((ext_vector_type(8))) short short8;
typedef __attribute__((ext_vector_type(4))) float float4v;

__device__ inline float bf2f(ushort u) {
    unsigned v = ((unsigned)u) << 16;
    return __builtin_bit_cast(float, v);
}
__device__ inline ushort f2bf(float f) {
    unsigned u = __builtin_bit_cast(unsigned, f);
    u += 0x7FFFu + ((u >> 16) & 1u);   // RNE
    return (ushort)(u >> 16);
}

// async global->LDS, 16B per lane; LDS dest = wave-uniform base + lane*16
__device__ inline void gload_lds16(const ushort* g, ushort* l) {
    __builtin_amdgcn_global_load_lds(
        (const __attribute__((address_space(1))) unsigned int*)g,
        (__attribute__((address_space(3))) unsigned int*)l,
        16, 0, 0);
}

// ---------------------------------------------------------------------------
// Kernel 1: hs fp32 -> bf16 [4096][1024] (pure BW pass)
// ---------------------------------------------------------------------------
__global__ __launch_bounds__(256) void convert_hs(
    const float* __restrict__ hs, ushort* __restrict__ hsb) {
    const size_t base = ((size_t)blockIdx.x * 256 + threadIdx.x) * 16;
    union { ushort u[16]; uint4 v[2]; } o;
#pragma unroll
    for (int q = 0; q < 4; ++q) {
        float4v f = *(const float4v*)(hs + base + q * 4);
#pragma unroll
        for (int j = 0; j < 4; ++j) o.u[q * 4 + j] = f2bf(f[j]);
    }
    *(uint4*)(hsb + base)     = o.v[0];
    *(uint4*)(hsb + base + 8) = o.v[1];
}

// ---------------------------------------------------------------------------
// Kernel 2: W fp32 [K][N] -> fused Wt bf16 [2048][1024] (Wq rows || Wv rows)
// ---------------------------------------------------------------------------
__global__ __launch_bounds__(256) void transpose_w(
    const float* __restrict__ Wq, const float* __restrict__ Wv,
    ushort* __restrict__ Wt) {
    __shared__ ushort tile[64][68];
    const float* W = blockIdx.z ? Wv : Wq;
    ushort* Wto    = Wt + (blockIdx.z ? (size_t)1024 * 1024 : 0);
    const int k0 = blockIdx.y * 64, n0 = blockIdx.x * 64;
    const int tid = threadIdx.x;
    const int rr = tid >> 4;          // 0..15
    const int cc = (tid & 15) * 4;    // 0..60
    union U4 { ushort u[4]; uint2 v; };
#pragma unroll
    for (int i = 0; i < 4; ++i) {
        int row = rr + i * 16;
        float4v f = *(const float4v*)(W + (size_t)(k0 + row) * 1024 + n0 + cc);
        U4 x;
#pragma unroll
        for (int j = 0; j < 4; ++j) x.u[j] = f2bf(f[j]);
        *(uint2*)&tile[row][cc] = x.v;
    }
    __syncthreads();
#pragma unroll
    for (int i = 0; i < 4; ++i) {
        int row = rr + i * 16;        // n within tile
        U4 o;
#pragma unroll
        for (int j = 0; j < 4; ++j) o.u[j] = tile[cc + j][row];
        *(uint2*)(Wto + (size_t)(n0 + row) * 1024 + k0 + cc) = o.v;
    }
}

// ---------------------------------------------------------------------------
// Kernel 3: fused Q|V GEMM, counted-vmcnt phase-split schedule (T2+T3+T4+T5).
//   C[4096][2048] = hsb[4096][1024] @ Wt[2048][1024]^T + bias, routed to
//   q_ws (cols 0..1023) / v_ws (cols 1024..2047) in [B][H][S][64] bf16.
//   BM=128, BN=256, BK=64; 512 thr = 8 waves (2M x 4N), 64x64 per wave.
//   LDS: 3 x 48KB K-tile buffers (A 16KB + B 32KB), depth-2 prefetch,
//   steady-state s_waitcnt vmcnt(6) (never 0 in main loop).
//   T2 swizzle: 16B chunk index ^= (row&7); gload_lds writes linearly, so
//   the swizzle is applied to the GLOBAL SOURCE address and on ds_read.
// ---------------------------------------------------------------------------
__global__ __launch_bounds__(512, 2) void qv_gemm(
    const ushort* __restrict__ hsb, const ushort* __restrict__ Wt,
    const float* __restrict__ bq, const float* __restrict__ bv,
    ushort* __restrict__ q_ws, ushort* __restrict__ v_ws) {
    __shared__ ushort smem[73728];                 // 3 * 49152 B
    const int m0 = blockIdx.y * 128, n0 = blockIdx.x * 256;
    const int tid  = threadIdx.x;
    const int wid  = tid >> 6, lane = tid & 63;
    const int quad = lane >> 4, l16 = lane & 15;
    const int wm = (wid >> 2) * 64;                // 0 / 64
    const int wn = (wid & 3) * 64;                 // 0 / 64 / 128 / 192
    const int srow8 = tid >> 3;                    // 0..63 (rows per 8KB round)
    const int scb   = (tid & 7) * 16;              // phys chunk byte 0..112

    // stage one 8KB round r (0,1: A rows; 2..5: B rows) of K-tile ktt -> buf bi
    auto stage = [&](int ktt, int bi, int r) {
        if (r < 2) {
            int row = r * 64 + srow8;                       // A row 0..127
            int sb  = scb ^ ((row & 7) << 4);               // inverse swizzle
            gload_lds16(hsb + (size_t)(m0 + row) * 1024 + ktt * 64 + (sb >> 1),
                        (ushort*)((char*)smem + bi * 49152 + r * 8192 + wid * 1024));
        } else {
            int row = (r - 2) * 64 + srow8;                 // B row 0..255
            int sb  = scb ^ ((row & 7) << 4);
            gload_lds16(Wt + (size_t)(n0 + row) * 1024 + ktt * 64 + (sb >> 1),
                        (ushort*)((char*)smem + bi * 49152 + 16384 + (r - 2) * 8192 + wid * 1024));
        }
    };

    float4v acc[4][4] = {};

    // prologue: tiles 0 and 1 in flight (12 loads/wave)
#pragma unroll
    for (int r = 0; r < 6; ++r) stage(0, 0, r);
#pragma unroll
    for (int r = 0; r < 6; ++r) stage(1, 1, r);

    int bi = 0;
    for (int ktt = 0; ktt < 16; ++ktt) {
        const char* Ab = (const char*)smem + bi * 49152;
        const char* Bb = Ab + 16384;

        // ---- group entry: tile ktt resident; newest 6 (tile ktt+1) may fly
        if (ktt < 15) asm volatile("s_waitcnt vmcnt(6)" ::: "memory");
        else          asm volatile("s_waitcnt vmcnt(0)" ::: "memory");
        __builtin_amdgcn_s_barrier();
        __builtin_amdgcn_sched_barrier(0);

        short8 af[4][2], bf0[2][2], bf1[2][2];
        // ---- phase A: read af (8) + bf nt=0,1 (4); stage rounds 0-2 of t+2
#pragma unroll
        for (int mt = 0; mt < 4; ++mt) {
            int ar = wm + mt * 16 + l16;
            int sw = (ar & 7) << 4;
#pragma unroll
            for (int ks = 0; ks < 2; ++ks)
                af[mt][ks] = *(const short8*)(Ab + ar * 128 + (((ks * 4 + quad) * 16) ^ sw));
        }
#pragma unroll
        for (int nt = 0; nt < 2; ++nt) {
            int br = wn + nt * 16 + l16;
            int sw = (br & 7) << 4;
#pragma unroll
            for (int ks = 0; ks < 2; ++ks)
                bf0[nt][ks] = *(const short8*)(Bb + br * 128 + (((ks * 4 + quad) * 16) ^ sw));
        }
        const int kn = ktt + 2;
        const int b2 = (bi + 2 >= 3) ? bi - 1 : bi + 2;
        if (kn < 16) { stage(kn, b2, 0); stage(kn, b2, 1); stage(kn, b2, 2); }
        __builtin_amdgcn_s_barrier();
        asm volatile("s_waitcnt lgkmcnt(0)" ::: "memory");
        __builtin_amdgcn_sched_barrier(0);
        __builtin_amdgcn_s_setprio(1);
#pragma unroll
        for (int ks = 0; ks < 2; ++ks)
#pragma unroll
            for (int mt = 0; mt < 4; ++mt) {
                acc[mt][0] = __builtin_amdgcn_mfma_f32_16x16x32_bf16(af[mt][ks], bf0[0][ks], acc[mt][0], 0, 0, 0);
                acc[mt][1] = __builtin_amdgcn_mfma_f32_16x16x32_bf16(af[mt][ks], bf0[1][ks], acc[mt][1], 0, 0, 0);
            }
        __builtin_amdgcn_s_setprio(0);

        // ---- phase B: read bf nt=2,3 (4); stage rounds 3-5 of t+2
#pragma unroll
        for (int nt = 0; nt < 2; ++nt) {
            int br = wn + (nt + 2) * 16 + l16;
            int sw = (br & 7) << 4;
#pragma unroll
            for (int ks = 0; ks < 2; ++ks)
                bf1[nt][ks] = *(const short8*)(Bb + br * 128 + (((ks * 4 + quad) * 16) ^ sw));
        }
        if (kn < 16) { stage(kn, b2, 3); stage(kn, b2, 4); stage(kn, b2, 5); }
        __builtin_amdgcn_s_barrier();
        asm volatile("s_waitcnt lgkmcnt(0)" ::: "memory");
        __builtin_amdgcn_sched_barrier(0);
        __builtin_amdgcn_s_setprio(1);
#pragma unroll
        for (int ks = 0; ks < 2; ++ks)
#pragma unroll
            for (int mt = 0; mt < 4; ++mt) {
                acc[mt][2] = __builtin_amdgcn_mfma_f32_16x16x32_bf16(af[mt][ks], bf1[0][ks], acc[mt][2], 0, 0, 0);
                acc[mt][3] = __builtin_amdgcn_mfma_f32_16x16x32_bf16(af[mt][ks], bf1[1][ks], acc[mt][3], 0, 0, 0);
            }
        __builtin_amdgcn_s_setprio(0);

        bi = (bi + 1 >= 3) ? 0 : bi + 1;
    }

    // ---- epilogue: bias + bf16 store routed to q_ws / v_ws ----
#pragma unroll
    for (int mt = 0; mt < 4; ++mt) {
#pragma unroll
        for (int nt = 0; nt < 4; ++nt) {
            int coln = n0 + wn + nt * 16 + l16;
            bool isq = coln < 1024;
            int c2 = isq ? coln : coln - 1024;
            float bsv = isq ? bq[c2] : bv[c2];
            ushort* outp = isq ? q_ws : v_ws;
            int hh = c2 >> 6, dd = c2 & 63;
#pragma unroll
            for (int reg = 0; reg < 4; ++reg) {
                int r = m0 + wm + mt * 16 + quad * 4 + reg;
                int bb = r >> 11, s = r & 2047;
                outp[(((size_t)bb * 16 + hh) * 2048 + s) * 64 + dd] =
                    f2bf(acc[mt][nt][reg] + bsv);
            }
        }
    }
}

// ---------------------------------------------------------------------------
// Kernel 4: MFMA fused sparse attention v3 (unchanged). 512 threads,
// 128-row x 256-col tile, 73.5 KB LDS -> 2 blocks/CU. Two-pass PV with
// P-half aliasing Kw; ctxp aliases Vt. XOR-chunk swizzles (<=2-way).
// ---------------------------------------------------------------------------
__global__ __launch_bounds__(512, 4) void attn(
    const ushort* __restrict__ q_ws, const ushort* __restrict__ v_ws,
    const float* __restrict__ amask, float* __restrict__ out) {
    const int t = blockIdx.x, h = blockIdx.y, b = blockIdx.z;

    __shared__ ushort KwPl[16384];   // Kw 256x64 (swz) -> later P-half 128x128 (swz)
    __shared__ ushort VtS[16384];    // V^T 64x256 (swz) -> later ctxp 128x64 fp32 (swz)
    __shared__ float  Sstr[128][17]; // strided scores -> probs
    __shared__ float  amw[256];      // window slice of attention_mask

    const int tid = threadIdx.x;     // 0..511
    const int wid = tid >> 6, lane = tid & 63;
    const int quad = lane >> 4, l16 = lane & 15;
    const int r0 = wid * 16;
    const size_t qbase = ((size_t)b * 16 + h) * 2048 * 64;
    const int base_row = (t - 1) * 128;
    const int nk = (t >= 2) ? (t - 1) : 0;

    // ---- stage ----
    if (tid < 256) {
        int j = base_row + tid; if (j < 0) j = 0;
        amw[tid] = amask[(size_t)b * 2048 + j];
    }
#pragma unroll
    for (int i = 0; i < 4; ++i) {
        int u = tid + i * 512;               // 256 rows x 8 chunks
        int row = u >> 3, c = u & 7;
        int jg = base_row + row; if (jg < 0) jg = 0;
        *(uint4*)&KwPl[row * 64 + ((c ^ (row & 7)) * 8)] =
            *(const uint4*)(q_ws + qbase + (size_t)jg * 64 + c * 8);
    }
    {   // Vt[d][j], swizzled: phys = d*256 + ((c ^ (d&7))*8) + (j&7)
        int j = tid & 255, dh0 = (tid >> 8) * 32;
        int jg = base_row + j; if (jg < 0) jg = 0;
        const ushort* src = v_ws + qbase + (size_t)jg * 64 + dh0;
        int cj = j >> 3, j7 = j & 7;
#pragma unroll
        for (int d = 0; d < 32; d += 8) {
            union { uint4 v; ushort u[8]; } tmp;
            tmp.v = *(const uint4*)(src + d);
#pragma unroll
            for (int jj = 0; jj < 8; ++jj) {
                int dd = dh0 + d + jj;
                VtS[dd * 256 + ((cj ^ (dd & 7)) * 8) + j7] = tmp.u[jj];
            }
        }
    }
    __syncthreads();

    // ---- QK^T: wave -> rows [r0,r0+16) x 256 cols ----
    float4v sacc[16] = {};
#pragma unroll
    for (int ks = 0; ks < 2; ++ks) {
        int c = ks * 4 + quad;
        int sw = (c ^ (l16 & 7)) * 8;
        short8 af = *(const short8*)&KwPl[(128 + r0 + l16) * 64 + sw];
#pragma unroll
        for (int nt = 0; nt < 16; ++nt) {
            short8 bfr = *(const short8*)&KwPl[(nt * 16 + l16) * 64 + sw];
            sacc[nt] = __builtin_amdgcn_mfma_f32_16x16x32_bf16(af, bfr, sacc[nt], 0, 0, 0);
        }
    }

    // ---- strided scores: 4 lanes/row, 16-d quarters ----
    const int sr = tid >> 2;             // 0..127
    const int dq = (tid & 3) * 16;
    if (nk > 0) {
        float qv[16];
#pragma unroll
        for (int cc = 0; cc < 2; ++cc) {
            int c = (dq >> 3) + cc;
            union { uint4 v; ushort u[8]; } tm;
            tm.v = *(const uint4*)&KwPl[(128 + sr) * 64 + ((c ^ (sr & 7)) * 8)];
#pragma unroll
            for (int jj = 0; jj < 8; ++jj) qv[cc * 8 + jj] = bf2f(tm.u[jj]);
        }
        for (int k = 0; k < nk; ++k) {
            const ushort* kr = q_ws + qbase + (size_t)(sr + (k << 7)) * 64 + dq;
            float p = 0.f;
#pragma unroll
            for (int d = 0; d < 16; d += 8) {
                union { uint4 v; ushort u[8]; } tm;
                tm.v = *(const uint4*)(kr + d);
#pragma unroll
                for (int jj = 0; jj < 8; ++jj) p += qv[d + jj] * bf2f(tm.u[jj]);
            }
            p += __shfl_xor(p, 1);
            p += __shfl_xor(p, 2);
            if ((tid & 3) == 0)
                Sstr[sr][k] = p * 0.125f + amask[(size_t)b * 2048 + sr + (k << 7)];
        }
    }
    __syncthreads();   // Kw dead; region becomes P-half

    // ---- softmax; write P-half1 (cols 0..127), stash half2 in regs ----
    unsigned pb[4][4];
#pragma unroll
    for (int reg = 0; reg < 4; ++reg) {
        int rr = r0 + quad * 4 + reg;
        float sv[16];
#pragma unroll
        for (int nt = 0; nt < 16; ++nt) {
            int c = nt * 16 + l16;
            bool allowed = (c >= rr) && (c <= rr + 128) && (t > 0 || c >= 128);
            sv[nt] = allowed ? sacc[nt][reg] * 0.125f + amw[c] : -INFINITY;
        }
        float sstr_v = (l16 < nk) ? Sstr[rr][l16] : -INFINITY;
        float m = sstr_v;
#pragma unroll
        for (int nt = 0; nt < 16; ++nt) m = fmaxf(m, sv[nt]);
#pragma unroll
        for (int off = 1; off < 16; off <<= 1) m = fmaxf(m, __shfl_xor(m, off));

        float es = (l16 < nk) ? __expf(sstr_v - m) : 0.f;
        float sum = es;
#pragma unroll
        for (int nt = 0; nt < 16; ++nt) {
            float e = (sv[nt] == -INFINITY) ? 0.f : __expf(sv[nt] - m);
            sv[nt] = e; sum += e;
        }
#pragma unroll
        for (int off = 1; off < 16; off <<= 1) sum += __shfl_xor(sum, off);
        float rden = 1.f / sum;
        // half1 -> LDS (P layout: phys = rr*128 + ((c ^ (rr&15))*8) + (j&7))
#pragma unroll
        for (int nt = 0; nt < 8; ++nt) {
            int c = nt * 2 + (l16 >> 3);
            KwPl[rr * 128 + ((c ^ (rr & 15)) * 8) + (l16 & 7)] = f2bf(sv[nt] * rden);
        }
        // half2 -> packed regs
#pragma unroll
        for (int i2 = 0; i2 < 4; ++i2) {
            unsigned lo = f2bf(sv[8 + 2 * i2] * rden);
            unsigned hi = f2bf(sv[9 + 2 * i2] * rden);
            pb[reg][i2] = lo | (hi << 16);
        }
        if (l16 < nk) Sstr[rr][l16] = es * rden;
    }
    __syncthreads();

    // ---- PV pass 1: P(cols 0..127) x Vt(j 0..127) ----
    float4v cacc[4] = {};
#pragma unroll
    for (int ks = 0; ks < 4; ++ks) {
        int cp = ks * 4 + quad;                       // P chunk 0..15
        short8 af = *(const short8*)&KwPl[(r0 + l16) * 128 + ((cp ^ l16) * 8)];
#pragma unroll
        for (int nt = 0; nt < 4; ++nt) {
            int sw = (cp ^ (l16 & 7)) * 8;            // Vt chunk 0..15
            short8 bfr = *(const short8*)&VtS[(nt * 16 + l16) * 256 + sw];
            cacc[nt] = __builtin_amdgcn_mfma_f32_16x16x32_bf16(af, bfr, cacc[nt], 0, 0, 0);
        }
    }
    __syncthreads();   // P-half1 reads done

    // ---- write P-half2 ----
#pragma unroll
    for (int reg = 0; reg < 4; ++reg) {
        int rr = r0 + quad * 4 + reg;
#pragma unroll
        for (int i2 = 0; i2 < 4; ++i2) {
            int nt0 = 8 + 2 * i2;
#pragma unroll
            for (int e2 = 0; e2 < 2; ++e2) {
                int nt = nt0 + e2;
                int c = (nt - 8) * 2 + (l16 >> 3);    // chunk 0..15 within half
                ushort val = (ushort)((pb[reg][i2] >> (16 * e2)) & 0xFFFF);
                KwPl[rr * 128 + ((c ^ (rr & 15)) * 8) + (l16 & 7)] = val;
            }
        }
    }
    __syncthreads();

    // ---- PV pass 2: P(cols 128..255) x Vt(j 128..255) ----
#pragma unroll
    for (int ks = 0; ks < 4; ++ks) {
        int cp = ks * 4 + quad;                       // chunk within half
        short8 af = *(const short8*)&KwPl[(r0 + l16) * 128 + ((cp ^ l16) * 8)];
#pragma unroll
        for (int nt = 0; nt < 4; ++nt) {
            int cv = 16 + cp;                         // Vt chunk 16..31
            int sw = (cv ^ (l16 & 7)) * 8;
            short8 bfr = *(const short8*)&VtS[(nt * 16 + l16) * 256 + sw];
            cacc[nt] = __builtin_amdgcn_mfma_f32_16x16x32_bf16(af, bfr, cacc[nt], 0, 0, 0);
        }
    }
    __syncthreads();   // Vt reads done; region becomes ctxp

    // ---- strided PV: 4 lanes/row, 16-d quarters -> ctxp (alias Vt) ----
    float* ctxp = (float*)&VtS[0];   // [128][64] fp32, chunk-swizzled
    {
        float acc16[16] = {};
        for (int k = 0; k < nk; ++k) {
            float p = Sstr[sr][k];
            const ushort* vr = v_ws + qbase + (size_t)(sr + (k << 7)) * 64 + dq;
#pragma unroll
            for (int d = 0; d < 16; d += 8) {
                union { uint4 v; ushort u[8]; } tm;
                tm.v = *(const uint4*)(vr + d);
#pragma unroll
                for (int jj = 0; jj < 8; ++jj) acc16[d + jj] += p * bf2f(tm.u[jj]);
            }
        }
#pragma unroll
        for (int d4 = 0; d4 < 4; ++d4) {
            int c = (dq >> 2) + d4;                   // float-chunk 0..15
            *(float4v*)&ctxp[sr * 64 + ((c ^ (sr & 15)) * 4)] =
                *(const float4v*)&acc16[d4 * 4];
        }
    }
    __syncthreads();

    // ---- epilogue: out[b][s][h*64+d], fp32 ----
    const size_t obase = ((size_t)b * 2048 + (size_t)t * 128) * 1024 + (size_t)h * 64;
#pragma unroll
    for (int nt = 0; nt < 4; ++nt)
#pragma unroll
        for (int reg = 0; reg < 4; ++reg) {
            int rr = r0 + quad * 4 + reg;
            int d = nt * 16 + l16;
            float cstr = ctxp[rr * 64 + (((d >> 2) ^ (rr & 15)) * 4) + (d & 3)];
            out[obase + (size_t)rr * 1024 + d] = cacc[nt][reg] + cstr;
        }
}

// ---------------------------------------------------------------------------
extern "C" void kernel_launch(void* const* d_in, const int* in_sizes, int n_in,
                              void* d_out, int out_size, void* d_ws, size_t ws_size,
                              hipStream_t stream) {
    int ihs = -1, iam = -1, iw1 = -1, iw2 = -1, ib1 = -1, ib2 = -1;
    for (int i = 0; i < n_in; ++i) {
        int s = in_sizes[i];
        if      (s == 4194304) { if (ihs < 0) ihs = i; }
        else if (s == 4096)    { if (iam < 0) iam = i; }
        else if (s == 1048576) { if (iw1 < 0) iw1 = i; else if (iw2 < 0) iw2 = i; }
        else if (s == 1024)    { if (ib1 < 0) ib1 = i; else if (ib2 < 0) ib2 = i; }
    }
    if (ihs < 0) ihs = 0; if (iam < 0) iam = 1;
    if (iw1 < 0) iw1 = 2; if (ib1 < 0) ib1 = 3;
    if (iw2 < 0) iw2 = 4; if (ib2 < 0) ib2 = 5;

    const float* hs    = (const float*)d_in[ihs];
    const float* amask = (const float*)d_in[iam];
    const float* Wq    = (const float*)d_in[iw1];
    const float* bq    = (const float*)d_in[ib1];
    const float* Wv    = (const float*)d_in[iw2];
    const float* bv    = (const float*)d_in[ib2];
    float* out = (float*)d_out;

    char* ws = (char*)d_ws;
    ushort* Wt   = (ushort*)(ws);                            // 4 MB fused [2048][1024]
    ushort* hsb  = (ushort*)(ws + (1u << 22));               // 8 MB
    ushort* q_ws = (ushort*)(ws + (1u << 22) + (1u << 23));  // 8 MB
    ushort* v_ws = (ushort*)(ws + (1u << 22) + (2u << 23));  // 8 MB

    convert_hs<<<1024, 256, 0, stream>>>(hs, hsb);
    transpose_w<<<dim3(16, 16, 2), 256, 0, stream>>>(Wq, Wv, Wt);
    qv_gemm<<<dim3(8, 32), 512, 0, stream>>>(hsb, Wt, bq, bv, q_ws, v_ws);
    attn<<<dim3(16, 16, 2), 512, 0, stream>>>(q_ws, v_ws, amask, out);
}

// Round 2
// 134.189 us; speedup vs baseline: 1.1118x; 1.0415x over previous
//
#include <hip/hip_runtime.h>

typedef __attribute__((ext_vector_type(8))) short short8;
typedef __attribute__((ext_vector_type(4))) float float4v;

__device__ inline float bf2f(ushort u) {
    unsigned v = ((unsigned)u) << 16;
    return __builtin_bit_cast(float, v);
}
__device__ inline ushort f2bf(float f) {
    unsigned u = __builtin_bit_cast(unsigned, f);
    u += 0x7FFFu + ((u >> 16) & 1u);   // RNE
    return (ushort)(u >> 16);
}

// async global->LDS, 16B per lane; LDS dest = wave-uniform base + lane*16
__device__ inline void gload_lds16(const ushort* g, ushort* l) {
    __builtin_amdgcn_global_load_lds(
        (const __attribute__((address_space(1))) unsigned int*)g,
        (__attribute__((address_space(3))) unsigned int*)l,
        16, 0, 0);
}

// ---------------------------------------------------------------------------
// Kernel 1: prep = convert_hs (blocks 0..1023) + transpose_w (blocks 1024..1535)
//   convert: hs fp32 -> hsb bf16 [4096][1024]
//   transpose: W fp32 [K][N] -> fused Wt bf16 [2048][1024] (Wq rows || Wv rows)
// ---------------------------------------------------------------------------
__global__ __launch_bounds__(256) void prep(
    const float* __restrict__ hs, ushort* __restrict__ hsb,
    const float* __restrict__ Wq, const float* __restrict__ Wv,
    ushort* __restrict__ Wt) {
    __shared__ ushort tile[64][68];
    if (blockIdx.x < 1024) {
        const size_t base = ((size_t)blockIdx.x * 256 + threadIdx.x) * 16;
        union { ushort u[16]; uint4 v[2]; } o;
#pragma unroll
        for (int q = 0; q < 4; ++q) {
            float4v f = *(const float4v*)(hs + base + q * 4);
#pragma unroll
            for (int j = 0; j < 4; ++j) o.u[q * 4 + j] = f2bf(f[j]);
        }
        *(uint4*)(hsb + base)     = o.v[0];
        *(uint4*)(hsb + base + 8) = o.v[1];
        return;
    }
    const int idx = blockIdx.x - 1024;
    const int z = idx >> 8, yy = (idx >> 4) & 15, xx = idx & 15;
    const float* W = z ? Wv : Wq;
    ushort* Wto    = Wt + (z ? (size_t)1024 * 1024 : 0);
    const int k0 = yy * 64, n0 = xx * 64;
    const int tid = threadIdx.x;
    const int rr = tid >> 4;          // 0..15
    const int cc = (tid & 15) * 4;    // 0..60
    union U4 { ushort u[4]; uint2 v; };
#pragma unroll
    for (int i = 0; i < 4; ++i) {
        int row = rr + i * 16;
        float4v f = *(const float4v*)(W + (size_t)(k0 + row) * 1024 + n0 + cc);
        U4 x;
#pragma unroll
        for (int j = 0; j < 4; ++j) x.u[j] = f2bf(f[j]);
        *(uint2*)&tile[row][cc] = x.v;
    }
    __syncthreads();
#pragma unroll
    for (int i = 0; i < 4; ++i) {
        int row = rr + i * 16;        // n within tile
        U4 o;
#pragma unroll
        for (int j = 0; j < 4; ++j) o.u[j] = tile[cc + j][row];
        *(uint2*)(Wto + (size_t)(n0 + row) * 1024 + k0 + cc) = o.v;
    }
}

// ---------------------------------------------------------------------------
// Kernel 2: fused Q|V GEMM. One barrier per K-tile; all 16 fragment reads
// issued up front (ks0 group / stages / ks1 group, order pinned), then
// lgkmcnt(8) -> MFMA ks0 overlapped with ks1 reads draining, lgkmcnt(0) ->
// MFMA ks1. Counted vmcnt(6) across iterations (T4); LDS XOR swizzle (T2)
// via inverse-swizzled global source; setprio around MFMA clusters (T5).
//   C[4096][2048] = hsb[4096][1024] @ Wt[2048][1024]^T + bias -> q_ws/v_ws.
//   BM=128, BN=256, BK=64; 512 thr = 8 waves (2M x 4N), 64x64 per wave.
//   LDS: 3 x 48KB K-tile buffers, depth-2 prefetch.
// ---------------------------------------------------------------------------
__global__ __launch_bounds__(512, 2) void qv_gemm(
    const ushort* __restrict__ hsb, const ushort* __restrict__ Wt,
    const float* __restrict__ bq, const float* __restrict__ bv,
    ushort* __restrict__ q_ws, ushort* __restrict__ v_ws) {
    __shared__ ushort smem[73728];                 // 3 * 49152 B
    const int m0 = blockIdx.y * 128, n0 = blockIdx.x * 256;
    const int tid  = threadIdx.x;
    const int wid  = tid >> 6, lane = tid & 63;
    const int quad = lane >> 4, l16 = lane & 15;
    const int wm = (wid >> 2) * 64;                // 0 / 64
    const int wn = (wid & 3) * 64;                 // 0 / 64 / 128 / 192
    const int srow8 = tid >> 3;                    // 0..63 (rows per 8KB round)
    const int scb   = (tid & 7) * 16;              // phys chunk byte 0..112

    // stage one 8KB round r (0,1: A rows; 2..5: B rows) of K-tile ktt -> buf bi
    auto stage = [&](int ktt, int bi, int r) {
        if (r < 2) {
            int row = r * 64 + srow8;                       // A row 0..127
            int sb  = scb ^ ((row & 7) << 4);               // inverse swizzle
            gload_lds16(hsb + (size_t)(m0 + row) * 1024 + ktt * 64 + (sb >> 1),
                        (ushort*)((char*)smem + bi * 49152 + r * 8192 + wid * 1024));
        } else {
            int row = (r - 2) * 64 + srow8;                 // B row 0..255
            int sb  = scb ^ ((row & 7) << 4);
            gload_lds16(Wt + (size_t)(n0 + row) * 1024 + ktt * 64 + (sb >> 1),
                        (ushort*)((char*)smem + bi * 49152 + 16384 + (r - 2) * 8192 + wid * 1024));
        }
    };

    float4v acc[4][4] = {};

    // prologue: tiles 0 and 1 in flight (12 loads/wave)
#pragma unroll
    for (int r = 0; r < 6; ++r) stage(0, 0, r);
#pragma unroll
    for (int r = 0; r < 6; ++r) stage(1, 1, r);

    int bi = 0;
    for (int ktt = 0; ktt < 16; ++ktt) {
        const char* Ab = (const char*)smem + bi * 49152;
        const char* Bb = Ab + 16384;

        // tile ktt resident after this wait+barrier; tile ktt+1's 6 stay in flight
        if (ktt < 15) asm volatile("s_waitcnt vmcnt(6)" ::: "memory");
        else          asm volatile("s_waitcnt vmcnt(0)" ::: "memory");
        __builtin_amdgcn_s_barrier();
        __builtin_amdgcn_sched_barrier(0);

        short8 af[4][2], bfr[4][2];
        // ---- read group 1: ks=0 fragments (8 x ds_read_b128)
#pragma unroll
        for (int mt = 0; mt < 4; ++mt) {
            int ar = wm + mt * 16 + l16;
            int sw = (ar & 7) << 4;
            af[mt][0] = *(const short8*)(Ab + ar * 128 + ((quad * 16) ^ sw));
        }
#pragma unroll
        for (int nt = 0; nt < 4; ++nt) {
            int br = wn + nt * 16 + l16;
            int sw = (br & 7) << 4;
            bfr[nt][0] = *(const short8*)(Bb + br * 128 + ((quad * 16) ^ sw));
        }
        __builtin_amdgcn_sched_barrier(0);
        // ---- stage K-tile ktt+2 (6 x global_load_lds, vmcnt only)
        const int kn = ktt + 2;
        const int b2 = (bi + 2 >= 3) ? bi - 1 : bi + 2;
        if (kn < 16) {
            stage(kn, b2, 0); stage(kn, b2, 1); stage(kn, b2, 2);
            stage(kn, b2, 3); stage(kn, b2, 4); stage(kn, b2, 5);
        }
        // ---- read group 2: ks=1 fragments (8 x ds_read_b128)
#pragma unroll
        for (int mt = 0; mt < 4; ++mt) {
            int ar = wm + mt * 16 + l16;
            int sw = (ar & 7) << 4;
            af[mt][1] = *(const short8*)(Ab + ar * 128 + (((4 + quad) * 16) ^ sw));
        }
#pragma unroll
        for (int nt = 0; nt < 4; ++nt) {
            int br = wn + nt * 16 + l16;
            int sw = (br & 7) << 4;
            bfr[nt][1] = *(const short8*)(Bb + br * 128 + (((4 + quad) * 16) ^ sw));
        }
        __builtin_amdgcn_sched_barrier(0);
        // ---- MFMA ks0 while ks1 reads drain (in-order LDS retire)
        asm volatile("s_waitcnt lgkmcnt(8)" ::: "memory");
        __builtin_amdgcn_sched_barrier(0);
        __builtin_amdgcn_s_setprio(1);
#pragma unroll
        for (int mt = 0; mt < 4; ++mt)
#pragma unroll
            for (int nt = 0; nt < 4; ++nt)
                acc[mt][nt] = __builtin_amdgcn_mfma_f32_16x16x32_bf16(
                    af[mt][0], bfr[nt][0], acc[mt][nt], 0, 0, 0);
        __builtin_amdgcn_s_setprio(0);
        asm volatile("s_waitcnt lgkmcnt(0)" ::: "memory");
        __builtin_amdgcn_sched_barrier(0);
        __builtin_amdgcn_s_setprio(1);
#pragma unroll
        for (int mt = 0; mt < 4; ++mt)
#pragma unroll
            for (int nt = 0; nt < 4; ++nt)
                acc[mt][nt] = __builtin_amdgcn_mfma_f32_16x16x32_bf16(
                    af[mt][1], bfr[nt][1], acc[mt][nt], 0, 0, 0);
        __builtin_amdgcn_s_setprio(0);

        bi = (bi + 1 >= 3) ? 0 : bi + 1;
    }

    // ---- epilogue: bias + bf16 store routed to q_ws / v_ws ----
#pragma unroll
    for (int mt = 0; mt < 4; ++mt) {
#pragma unroll
        for (int nt = 0; nt < 4; ++nt) {
            int coln = n0 + wn + nt * 16 + l16;
            bool isq = coln < 1024;
            int c2 = isq ? coln : coln - 1024;
            float bsv = isq ? bq[c2] : bv[c2];
            ushort* outp = isq ? q_ws : v_ws;
            int hh = c2 >> 6, dd = c2 & 63;
#pragma unroll
            for (int reg = 0; reg < 4; ++reg) {
                int r = m0 + wm + mt * 16 + quad * 4 + reg;
                int bb = r >> 11, s = r & 2047;
                outp[(((size_t)bb * 16 + hh) * 2048 + s) * 64 + dd] =
                    f2bf(acc[mt][nt][reg] + bsv);
            }
        }
    }
}

// ---------------------------------------------------------------------------
// Kernel 3: MFMA fused sparse attention v3 + software-pipelined strided loops.
// 512 threads, 128-row x 256-col tile, 73.5 KB LDS -> 2 blocks/CU.
// ---------------------------------------------------------------------------
__global__ __launch_bounds__(512, 4) void attn(
    const ushort* __restrict__ q_ws, const ushort* __restrict__ v_ws,
    const float* __restrict__ amask, float* __restrict__ out) {
    const int t = blockIdx.x, h = blockIdx.y, b = blockIdx.z;

    __shared__ ushort KwPl[16384];   // Kw 256x64 (swz) -> later P-half 128x128 (swz)
    __shared__ ushort VtS[16384];    // V^T 64x256 (swz) -> later ctxp 128x64 fp32 (swz)
    __shared__ float  Sstr[128][17]; // strided scores -> probs
    __shared__ float  amw[256];      // window slice of attention_mask

    const int tid = threadIdx.x;     // 0..511
    const int wid = tid >> 6, lane = tid & 63;
    const int quad = lane >> 4, l16 = lane & 15;
    const int r0 = wid * 16;
    const size_t qbase = ((size_t)b * 16 + h) * 2048 * 64;
    const int base_row = (t - 1) * 128;
    const int nk = (t >= 2) ? (t - 1) : 0;

    // ---- stage ----
    if (tid < 256) {
        int j = base_row + tid; if (j < 0) j = 0;
        amw[tid] = amask[(size_t)b * 2048 + j];
    }
#pragma unroll
    for (int i = 0; i < 4; ++i) {
        int u = tid + i * 512;               // 256 rows x 8 chunks
        int row = u >> 3, c = u & 7;
        int jg = base_row + row; if (jg < 0) jg = 0;
        *(uint4*)&KwPl[row * 64 + ((c ^ (row & 7)) * 8)] =
            *(const uint4*)(q_ws + qbase + (size_t)jg * 64 + c * 8);
    }
    {   // Vt[d][j], swizzled: phys = d*256 + ((c ^ (d&7))*8) + (j&7)
        int j = tid & 255, dh0 = (tid >> 8) * 32;
        int jg = base_row + j; if (jg < 0) jg = 0;
        const ushort* src = v_ws + qbase + (size_t)jg * 64 + dh0;
        int cj = j >> 3, j7 = j & 7;
#pragma unroll
        for (int d = 0; d < 32; d += 8) {
            union { uint4 v; ushort u[8]; } tmp;
            tmp.v = *(const uint4*)(src + d);
#pragma unroll
            for (int jj = 0; jj < 8; ++jj) {
                int dd = dh0 + d + jj;
                VtS[dd * 256 + ((cj ^ (dd & 7)) * 8) + j7] = tmp.u[jj];
            }
        }
    }
    __syncthreads();

    // ---- QK^T: wave -> rows [r0,r0+16) x 256 cols ----
    float4v sacc[16] = {};
#pragma unroll
    for (int ks = 0; ks < 2; ++ks) {
        int c = ks * 4 + quad;
        int sw = (c ^ (l16 & 7)) * 8;
        short8 af = *(const short8*)&KwPl[(128 + r0 + l16) * 64 + sw];
#pragma unroll
        for (int nt = 0; nt < 16; ++nt) {
            short8 bfr = *(const short8*)&KwPl[(nt * 16 + l16) * 64 + sw];
            sacc[nt] = __builtin_amdgcn_mfma_f32_16x16x32_bf16(af, bfr, sacc[nt], 0, 0, 0);
        }
    }

    // ---- strided scores: 4 lanes/row, 16-d quarters; 1-deep prefetch ----
    const int sr = tid >> 2;             // 0..127
    const int dq = (tid & 3) * 16;
    if (nk > 0) {
        float qv[16];
#pragma unroll
        for (int cc = 0; cc < 2; ++cc) {
            int c = (dq >> 3) + cc;
            union { uint4 v; ushort u[8]; } tm;
            tm.v = *(const uint4*)&KwPl[(128 + sr) * 64 + ((c ^ (sr & 7)) * 8)];
#pragma unroll
            for (int jj = 0; jj < 8; ++jj) qv[cc * 8 + jj] = bf2f(tm.u[jj]);
        }
        const size_t rbase = qbase + (size_t)sr * 64 + dq;
        uint4 ta = *(const uint4*)(q_ws + rbase);
        uint4 tb = *(const uint4*)(q_ws + rbase + 8);
        float amc = amask[(size_t)b * 2048 + sr];
        for (int k = 0; k < nk; ++k) {
            uint4 na = ta, nb = tb; float amn = amc;
            if (k + 1 < nk) {
                const ushort* kr = q_ws + rbase + ((size_t)(k + 1) << 13);
                na = *(const uint4*)kr; nb = *(const uint4*)(kr + 8);
                amn = amask[(size_t)b * 2048 + sr + ((k + 1) << 7)];
            }
            union { uint4 v; ushort u[8]; } t0, t1;
            t0.v = ta; t1.v = tb;
            float p = 0.f;
#pragma unroll
            for (int jj = 0; jj < 8; ++jj) p += qv[jj] * bf2f(t0.u[jj]);
#pragma unroll
            for (int jj = 0; jj < 8; ++jj) p += qv[8 + jj] * bf2f(t1.u[jj]);
            p += __shfl_xor(p, 1);
            p += __shfl_xor(p, 2);
            if ((tid & 3) == 0)
                Sstr[sr][k] = p * 0.125f + amc;
            ta = na; tb = nb; amc = amn;
        }
    }
    __syncthreads();   // Kw dead; region becomes P-half

    // ---- softmax; write P-half1 (cols 0..127), stash half2 in regs ----
    unsigned pb[4][4];
#pragma unroll
    for (int reg = 0; reg < 4; ++reg) {
        int rr = r0 + quad * 4 + reg;
        float sv[16];
#pragma unroll
        for (int nt = 0; nt < 16; ++nt) {
            int c = nt * 16 + l16;
            bool allowed = (c >= rr) && (c <= rr + 128) && (t > 0 || c >= 128);
            sv[nt] = allowed ? sacc[nt][reg] * 0.125f + amw[c] : -INFINITY;
        }
        float sstr_v = (l16 < nk) ? Sstr[rr][l16] : -INFINITY;
        float m = sstr_v;
#pragma unroll
        for (int nt = 0; nt < 16; ++nt) m = fmaxf(m, sv[nt]);
#pragma unroll
        for (int off = 1; off < 16; off <<= 1) m = fmaxf(m, __shfl_xor(m, off));

        float es = (l16 < nk) ? __expf(sstr_v - m) : 0.f;
        float sum = es;
#pragma unroll
        for (int nt = 0; nt < 16; ++nt) {
            float e = (sv[nt] == -INFINITY) ? 0.f : __expf(sv[nt] - m);
            sv[nt] = e; sum += e;
        }
#pragma unroll
        for (int off = 1; off < 16; off <<= 1) sum += __shfl_xor(sum, off);
        float rden = 1.f / sum;
        // half1 -> LDS (P layout: phys = rr*128 + ((c ^ (rr&15))*8) + (j&7))
#pragma unroll
        for (int nt = 0; nt < 8; ++nt) {
            int c = nt * 2 + (l16 >> 3);
            KwPl[rr * 128 + ((c ^ (rr & 15)) * 8) + (l16 & 7)] = f2bf(sv[nt] * rden);
        }
        // half2 -> packed regs
#pragma unroll
        for (int i2 = 0; i2 < 4; ++i2) {
            unsigned lo = f2bf(sv[8 + 2 * i2] * rden);
            unsigned hi = f2bf(sv[9 + 2 * i2] * rden);
            pb[reg][i2] = lo | (hi << 16);
        }
        if (l16 < nk) Sstr[rr][l16] = es * rden;
    }
    __syncthreads();

    // ---- PV pass 1: P(cols 0..127) x Vt(j 0..127) ----
    float4v cacc[4] = {};
#pragma unroll
    for (int ks = 0; ks < 4; ++ks) {
        int cp = ks * 4 + quad;                       // P chunk 0..15
        short8 af = *(const short8*)&KwPl[(r0 + l16) * 128 + ((cp ^ l16) * 8)];
#pragma unroll
        for (int nt = 0; nt < 4; ++nt) {
            int sw = (cp ^ (l16 & 7)) * 8;            // Vt chunk 0..15
            short8 bfr = *(const short8*)&VtS[(nt * 16 + l16) * 256 + sw];
            cacc[nt] = __builtin_amdgcn_mfma_f32_16x16x32_bf16(af, bfr, cacc[nt], 0, 0, 0);
        }
    }
    __syncthreads();   // P-half1 reads done

    // ---- write P-half2 ----
#pragma unroll
    for (int reg = 0; reg < 4; ++reg) {
        int rr = r0 + quad * 4 + reg;
#pragma unroll
        for (int i2 = 0; i2 < 4; ++i2) {
            int nt0 = 8 + 2 * i2;
#pragma unroll
            for (int e2 = 0; e2 < 2; ++e2) {
                int nt = nt0 + e2;
                int c = (nt - 8) * 2 + (l16 >> 3);    // chunk 0..15 within half
                ushort val = (ushort)((pb[reg][i2] >> (16 * e2)) & 0xFFFF);
                KwPl[rr * 128 + ((c ^ (rr & 15)) * 8) + (l16 & 7)] = val;
            }
        }
    }
    __syncthreads();

    // ---- PV pass 2: P(cols 128..255) x Vt(j 128..255) ----
#pragma unroll
    for (int ks = 0; ks < 4; ++ks) {
        int cp = ks * 4 + quad;                       // chunk within half
        short8 af = *(const short8*)&KwPl[(r0 + l16) * 128 + ((cp ^ l16) * 8)];
#pragma unroll
        for (int nt = 0; nt < 4; ++nt) {
            int cv = 16 + cp;                         // Vt chunk 16..31
            int sw = (cv ^ (l16 & 7)) * 8;
            short8 bfr = *(const short8*)&VtS[(nt * 16 + l16) * 256 + sw];
            cacc[nt] = __builtin_amdgcn_mfma_f32_16x16x32_bf16(af, bfr, cacc[nt], 0, 0, 0);
        }
    }
    __syncthreads();   // Vt reads done; region becomes ctxp

    // ---- strided PV: 4 lanes/row, 16-d quarters, 1-deep prefetch ----
    float* ctxp = (float*)&VtS[0];   // [128][64] fp32, chunk-swizzled
    {
        float acc16[16] = {};
        const size_t rbase = qbase + (size_t)sr * 64 + dq;
        if (nk > 0) {
            uint4 ta = *(const uint4*)(v_ws + rbase);
            uint4 tb = *(const uint4*)(v_ws + rbase + 8);
            for (int k = 0; k < nk; ++k) {
                uint4 na = ta, nb = tb;
                if (k + 1 < nk) {
                    const ushort* vr = v_ws + rbase + ((size_t)(k + 1) << 13);
                    na = *(const uint4*)vr; nb = *(const uint4*)(vr + 8);
                }
                float p = Sstr[sr][k];
                union { uint4 v; ushort u[8]; } t0, t1;
                t0.v = ta; t1.v = tb;
#pragma unroll
                for (int jj = 0; jj < 8; ++jj) acc16[jj] += p * bf2f(t0.u[jj]);
#pragma unroll
                for (int jj = 0; jj < 8; ++jj) acc16[8 + jj] += p * bf2f(t1.u[jj]);
                ta = na; tb = nb;
            }
        }
#pragma unroll
        for (int d4 = 0; d4 < 4; ++d4) {
            int c = (dq >> 2) + d4;                   // float-chunk 0..15
            *(float4v*)&ctxp[sr * 64 + ((c ^ (sr & 15)) * 4)] =
                *(const float4v*)&acc16[d4 * 4];
        }
    }
    __syncthreads();

    // ---- epilogue: out[b][s][h*64+d], fp32 ----
    const size_t obase = ((size_t)b * 2048 + (size_t)t * 128) * 1024 + (size_t)h * 64;
#pragma unroll
    for (int nt = 0; nt < 4; ++nt)
#pragma unroll
        for (int reg = 0; reg < 4; ++reg) {
            int rr = r0 + quad * 4 + reg;
            int d = nt * 16 + l16;
            float cstr = ctxp[rr * 64 + (((d >> 2) ^ (rr & 15)) * 4) + (d & 3)];
            out[obase + (size_t)rr * 1024 + d] = cacc[nt][reg] + cstr;
        }
}

// ---------------------------------------------------------------------------
extern "C" void kernel_launch(void* const* d_in, const int* in_sizes, int n_in,
                              void* d_out, int out_size, void* d_ws, size_t ws_size,
                              hipStream_t stream) {
    int ihs = -1, iam = -1, iw1 = -1, iw2 = -1, ib1 = -1, ib2 = -1;
    for (int i = 0; i < n_in; ++i) {
        int s = in_sizes[i];
        if      (s == 4194304) { if (ihs < 0) ihs = i; }
        else if (s == 4096)    { if (iam < 0) iam = i; }
        else if (s == 1048576) { if (iw1 < 0) iw1 = i; else if (iw2 < 0) iw2 = i; }
        else if (s == 1024)    { if (ib1 < 0) ib1 = i; else if (ib2 < 0) ib2 = i; }
    }
    if (ihs < 0) ihs = 0; if (iam < 0) iam = 1;
    if (iw1 < 0) iw1 = 2; if (ib1 < 0) ib1 = 3;
    if (iw2 < 0) iw2 = 4; if (ib2 < 0) ib2 = 5;

    const float* hs    = (const float*)d_in[ihs];
    const float* amask = (const float*)d_in[iam];
    const float* Wq    = (const float*)d_in[iw1];
    const float* bq    = (const float*)d_in[ib1];
    const float* Wv    = (const float*)d_in[iw2];
    const float* bv    = (const float*)d_in[ib2];
    float* out = (float*)d_out;

    char* ws = (char*)d_ws;
    ushort* Wt   = (ushort*)(ws);                            // 4 MB fused [2048][1024]
    ushort* hsb  = (ushort*)(ws + (1u << 22));               // 8 MB
    ushort* q_ws = (ushort*)(ws + (1u << 22) + (1u << 23));  // 8 MB
    ushort* v_ws = (ushort*)(ws + (1u << 22) + (2u << 23));  // 8 MB

    prep<<<1536, 256, 0, stream>>>(hs, hsb, Wq, Wv, Wt);
    qv_gemm<<<dim3(8, 32), 512, 0, stream>>>(hsb, Wt, bq, bv, q_ws, v_ws);
    attn<<<dim3(16, 16, 2), 512, 0, stream>>>(q_ws, v_ws, amask, out);
}